// Round 8
// baseline (197.921 us; speedup 1.0000x reference)
//
#include <hip/hip_runtime.h>
#include <hip/hip_bf16.h>
#include <math.h>

#define ICH   3
#define OCH   16
#define ID    18
#define IH    34
#define IW    34
#define OD    16
#define OH    32
#define OW    32
#define NB    128
#define PLANE_W  36                 // padded row stride (floats)
#define SROWS    18                 // 16 output rows + 2 halo
#define PLANE_SZ (PLANE_W * SROWS)  // 648 floats
#define NPLANES  9                  // 3 ic x 3 kd input planes for ONE output d
#define SPATIAL  (OD * OH * OW)     // 16384 per (b,c)
#define EPSV     1e-5f

__device__ __forceinline__ unsigned short f2bf(float f) {
    unsigned int u = __float_as_uint(f);
    unsigned int r = (u + 0x7fffu + ((u >> 16) & 1u)) >> 16;
    return (unsigned short)r;
}

// ===== conv v3: occupancy-first tile. One block per (b, d, h-band of 16).
// Staged tile: 9 planes (3ic x 3kd) x 18 rows x 34 cols fp32 = 23.3 KB LDS
// -> 6 blocks/CU (24 waves/CU, 3x the R1 structure) to hide ds_read/s_load
// latency that capped VALUBusy at 48%. acc[16][2] = 32 live accumulator regs.
// Keep: compile-time weight idx (s_load path), fp32 staging, (256,2) bounds.
// Do NOT: raise min-waves (spill: R2/R3), fp16 staging (cvt+scratch: R5),
// transposed y scatter-stores (R7: conv +6 us).
__global__ __launch_bounds__(256, 2) void conv_stats_kernel(
    const float* __restrict__ x, const float* __restrict__ cw,
    const float* __restrict__ cb, const float* __restrict__ mult,
    unsigned short* __restrict__ y, float* __restrict__ stats)
{
    __shared__ float sx[NPLANES][PLANE_SZ];   // 23328 B
    __shared__ float wsum[4][OCH], wsq[4][OCH];

    const int blk = blockIdx.x;
    const int b  = blk >> 5;
    const int d  = (blk >> 1) & 15;
    const int h0 = (blk & 1) << 4;
    const int tid = threadIdx.x;

    // ---- stage 9 planes x 18 rows x 34 cols as float2 (2754 slots) ----
    for (int i = tid; i < NPLANES * SROWS * 17; i += 256) {
        const int plane = i / 306;                  // 306 = 18*17 (magic-mul)
        const int rem   = i - plane * 306;
        const int row   = rem / 17;
        const int col2  = (rem - row * 17) * 2;
        const int ic = plane / 3, kd = plane - ic * 3;  // const-div
        const float2 v = *(const float2*)&x[
            ((size_t)(b * ICH + ic) * ID + (d + kd)) * (IH * IW)
            + (size_t)(h0 + row) * IW + col2];
        *(float2*)&sx[plane][row * PLANE_W + col2] = v;
    }
    __syncthreads();

    const int h  = tid >> 4;        // 0..15
    const int w0 = (tid & 15) << 1; // 0,2,...,30

    float acc[OCH][2];
#pragma unroll
    for (int c = 0; c < OCH; c++) {
        const float bv = cb[c];
        acc[c][0] = bv; acc[c][1] = bv;
    }

#pragma unroll
    for (int ic = 0; ic < ICH; ic++) {
#pragma unroll
        for (int kd = 0; kd < 3; kd++) {
            const float* pl = &sx[ic * 3 + kd][0];
#pragma unroll
            for (int kh = 0; kh < 3; kh++) {
                const float* row = pl + (h + kh) * PLANE_W + w0;   // 8B aligned
                const float2 v0 = *(const float2*)row;
                const float2 v1 = *(const float2*)(row + 2);
                float in[4];
                in[0] = v0.x; in[1] = v0.y; in[2] = v1.x; in[3] = v1.y;
                const float* wrow = &cw[(size_t)(ic * 3 + kd) * 9 + kh * 3];
#pragma unroll
                for (int kw = 0; kw < 3; kw++) {
#pragma unroll
                    for (int c = 0; c < OCH; c++) {
                        const float wv = wrow[(size_t)c * (ICH * 27) + kw];  // s_load
                        acc[c][0] = fmaf(in[kw + 0], wv, acc[c][0]);
                        acc[c][1] = fmaf(in[kw + 1], wv, acc[c][1]);
                    }
                }
            }
        }
    }

    // ---- multiplier fold, stats, bf16 store (channel-major y) ----
    float ssum[OCH], ssq[OCH];
#pragma unroll
    for (int c = 0; c < OCH; c++) {
        const float m = mult[c];
        const float o0 = acc[c][0] * m, o1 = acc[c][1] * m;
        ssum[c] = o0 + o1;
        ssq[c]  = o0 * o0 + o1 * o1;
        const size_t yi = ((size_t)(b * OCH + c) * OD + d) * (OH * OW)
                          + (size_t)(h0 + h) * OW + w0;
        const unsigned int pk = (unsigned int)f2bf(o0) | ((unsigned int)f2bf(o1) << 16);
        *(unsigned int*)&y[yi] = pk;
    }

    // ---- block reduction of stats, one atomicAdd per (b,c) ----
#pragma unroll
    for (int c = 0; c < OCH; c++) {
        for (int off = 32; off > 0; off >>= 1) {
            ssum[c] += __shfl_down(ssum[c], off);
            ssq[c]  += __shfl_down(ssq[c], off);
        }
    }
    const int wave = tid >> 6, lane = tid & 63;
    if (lane == 0) {
#pragma unroll
        for (int c = 0; c < OCH; c++) { wsum[wave][c] = ssum[c]; wsq[wave][c] = ssq[c]; }
    }
    __syncthreads();
    if (tid < OCH) {
        float s = 0.0f, q = 0.0f;
#pragma unroll
        for (int k = 0; k < 4; k++) { s += wsum[k][tid]; q += wsq[k][tid]; }
        atomicAdd(&stats[(b * OCH + tid) * 2 + 0], s);
        atomicAdd(&stats[(b * OCH + tid) * 2 + 1], q);
    }
}

// ===== norm_max (R6 v3 — best-total config). 2048 blocks, 4 positions/thread,
// all 16 channel loads hoisted before use.
__global__ __launch_bounds__(256, 2) void norm_max_kernel(
    const unsigned short* __restrict__ y, const float* __restrict__ stats,
    const float* __restrict__ mult, float* __restrict__ out)
{
    const int blk = blockIdx.x;
    const int b   = blk >> 4;
    const int seg = blk & 15;
    const int tid = threadIdx.x;

    __shared__ float srs_s[OCH], snb_s[OCH], smul_s[OCH];
    if (tid < OCH) {
        const float s  = stats[(b * OCH + tid) * 2 + 0];
        const float sq = stats[(b * OCH + tid) * 2 + 1];
        const float mean = s * (1.0f / (float)SPATIAL);
        float var = sq * (1.0f / (float)SPATIAL) - mean * mean;
        var = fmaxf(var, 0.0f);
        const float rs = rsqrtf(var + EPSV);
        srs_s[tid]  = rs;
        snb_s[tid]  = -mean * rs;      // normalized = v*rs + nb
        smul_s[tid] = mult[tid];
    }
    __syncthreads();

    const int s = seg * 1024 + tid * 4;
    const unsigned short* yb = y + (size_t)b * OCH * SPATIAL + s;

    uint2 v[OCH];
#pragma unroll
    for (int c = 0; c < OCH; c++) {
        v[c] = *(const uint2*)(yb + (size_t)c * SPATIAL);
    }

    float rs[OCH], nb[OCH], mm[OCH];
#pragma unroll
    for (int c = 0; c < OCH; c++) { rs[c] = srs_s[c]; nb[c] = snb_s[c]; mm[c] = smul_s[c]; }

    float b0 = -INFINITY, b1 = -INFINITY, b2 = -INFINITY, b3 = -INFINITY;
#pragma unroll
    for (int c = 0; c < OCH; c++) {
        float f0 = __uint_as_float(v[c].x << 16)         * rs[c] + nb[c];
        float f1 = __uint_as_float(v[c].x & 0xffff0000u) * rs[c] + nb[c];
        float f2 = __uint_as_float(v[c].y << 16)         * rs[c] + nb[c];
        float f3 = __uint_as_float(v[c].y & 0xffff0000u) * rs[c] + nb[c];
        f0 = fminf(fmaxf(f0, -1.0f), 1.0f) * mm[c];
        f1 = fminf(fmaxf(f1, -1.0f), 1.0f) * mm[c];
        f2 = fminf(fmaxf(f2, -1.0f), 1.0f) * mm[c];
        f3 = fminf(fmaxf(f3, -1.0f), 1.0f) * mm[c];
        b0 = fmaxf(b0, f0); b1 = fmaxf(b1, f1);
        b2 = fmaxf(b2, f2); b3 = fmaxf(b3, f3);
    }
    float4 o; o.x = b0; o.y = b1; o.z = b2; o.w = b3;
    *(float4*)&out[(size_t)b * SPATIAL + s] = o;
}

extern "C" void kernel_launch(void* const* d_in, const int* in_sizes, int n_in,
                              void* d_out, int out_size, void* d_ws, size_t ws_size,
                              hipStream_t stream) {
    const float* x    = (const float*)d_in[0];
    const float* cw   = (const float*)d_in[1];
    const float* cb   = (const float*)d_in[2];
    const float* mult = (const float*)d_in[3];
    float* out = (float*)d_out;

    unsigned short* y = (unsigned short*)d_ws;   // channel-major, 64 MB
    float* stats = (float*)((char*)d_ws + (size_t)NB * OCH * SPATIAL * sizeof(unsigned short));

    hipMemsetAsync(stats, 0, (size_t)NB * OCH * 2 * sizeof(float), stream);
    conv_stats_kernel<<<NB * OD * 2, 256, 0, stream>>>(x, cw, cb, mult, y, stats);
    norm_max_kernel<<<NB * 16, 256, 0, stream>>>(y, stats, mult, out);
}

// Round 9
// 161.671 us; speedup vs baseline: 1.2242x; 1.2242x over previous
//
#include <hip/hip_runtime.h>
#include <hip/hip_bf16.h>
#include <math.h>

#define ICH   3
#define OCH   16
#define ID    18
#define IH    34
#define IW    34
#define OD    16
#define OH    32
#define OW    32
#define NB    128
#define DCHUNK   2
#define SPATIAL  (OD * OH * OW)     // 16384 per (b,c)
#define EPSV     1e-5f

__device__ __forceinline__ unsigned short f2bf(float f) {
    unsigned int u = __float_as_uint(f);
    unsigned int r = (u + 0x7fffu + ((u >> 16) & 1u)) >> 16;
    return (unsigned short)r;
}

// ===== conv v4: NO LDS STAGING. R1's exact compute loop (proven best:
// in-thread dz reuse, all-16-oc unroll, runtime-uniform ic/kd weight idx ->
// s_load path, 4 w/thread), but input rows read DIRECTLY from global x.
// A block's x-footprint (~59 KB) is L1/L2-resident; adjacent threads share
// cache lines (halo). Removes: staging loop (58 scalar loads + div/mod),
// vmcnt(0) drain, both barriers -> the synchronized all-wave stalls that
// capped VALUBusy at 48%; occupancy no longer LDS-capped.
// Do NOT: raise min-waves (R2/R3 spill), fp16 staging (R5), transpose y (R7),
// shrink per-thread FMA volume (R8).
__global__ __launch_bounds__(256, 2) void conv_stats_kernel(
    const float* __restrict__ x, const float* __restrict__ cw,
    const float* __restrict__ cb, const float* __restrict__ mult,
    unsigned short* __restrict__ y, float* __restrict__ stats)
{
    __shared__ float wsum[4][OCH], wsq[4][OCH];

    const int blk = blockIdx.x;
    const int b = blk >> 3;
    const int d0 = (blk & 7) * DCHUNK;
    const int tid = threadIdx.x;

    const int h  = tid >> 3;        // 0..31
    const int wq = (tid & 7) << 2;  // 0,4,...,28

    float ssum[OCH], ssq[OCH];
#pragma unroll
    for (int c = 0; c < OCH; c++) { ssum[c] = 0.0f; ssq[c] = 0.0f; }

    for (int dz = 0; dz < DCHUNK; dz++) {
        float acc[OCH][4];
#pragma unroll
        for (int c = 0; c < OCH; c++) {
            const float bv = cb[c];
            acc[c][0] = bv; acc[c][1] = bv; acc[c][2] = bv; acc[c][3] = bv;
        }

        for (int ic = 0; ic < ICH; ic++) {
            for (int kd = 0; kd < 3; kd++) {
                const float* plane = x + ((size_t)(b * ICH + ic) * ID + (d0 + dz + kd)) * (IH * IW);
#pragma unroll
                for (int kh = 0; kh < 3; kh++) {
                    const float* row = plane + (size_t)(h + kh) * IW + wq;
                    const float4 v0 = *(const float4*)row;      // 4B-aligned dwordx4 (ok on global)
                    const float2 v1 = *(const float2*)(row + 4);
                    float in[6];
                    in[0] = v0.x; in[1] = v0.y; in[2] = v0.z; in[3] = v0.w;
                    in[4] = v1.x; in[5] = v1.y;
                    const float* wrow = &cw[(size_t)(ic * 3 + kd) * 9 + kh * 3];
#pragma unroll
                    for (int kw = 0; kw < 3; kw++) {
#pragma unroll
                        for (int c = 0; c < OCH; c++) {
                            const float wv = wrow[(size_t)c * (ICH * 27) + kw];  // uniform -> s_load
                            acc[c][0] = fmaf(in[kw + 0], wv, acc[c][0]);
                            acc[c][1] = fmaf(in[kw + 1], wv, acc[c][1]);
                            acc[c][2] = fmaf(in[kw + 2], wv, acc[c][2]);
                            acc[c][3] = fmaf(in[kw + 3], wv, acc[c][3]);
                        }
                    }
                }
            }
        }

        const int d = d0 + dz;
#pragma unroll
        for (int c = 0; c < OCH; c++) {
            const float m = mult[c];
            const float o0 = acc[c][0] * m, o1 = acc[c][1] * m;
            const float o2 = acc[c][2] * m, o3 = acc[c][3] * m;
            ssum[c] += (o0 + o1) + (o2 + o3);
            ssq[c]  += (o0 * o0 + o1 * o1) + (o2 * o2 + o3 * o3);
            const size_t yi = ((size_t)(b * OCH + c) * OD + d) * (OH * OW) + h * OW + wq;
            ushort4 pk;
            pk.x = f2bf(o0); pk.y = f2bf(o1); pk.z = f2bf(o2); pk.w = f2bf(o3);
            *(ushort4*)&y[yi] = pk;
        }
    }

#pragma unroll
    for (int c = 0; c < OCH; c++) {
        for (int off = 32; off > 0; off >>= 1) {
            ssum[c] += __shfl_down(ssum[c], off);
            ssq[c]  += __shfl_down(ssq[c], off);
        }
    }
    const int wave = tid >> 6, lane = tid & 63;
    if (lane == 0) {
#pragma unroll
        for (int c = 0; c < OCH; c++) { wsum[wave][c] = ssum[c]; wsq[wave][c] = ssq[c]; }
    }
    __syncthreads();
    if (tid < OCH) {
        float s = 0.0f, q = 0.0f;
#pragma unroll
        for (int k = 0; k < 4; k++) { s += wsum[k][tid]; q += wsq[k][tid]; }
        atomicAdd(&stats[(b * OCH + tid) * 2 + 0], s);
        atomicAdd(&stats[(b * OCH + tid) * 2 + 1], q);
    }
}

// ===== norm_max (R6 v3 — best-total config). 2048 blocks, 4 positions/thread,
// all 16 channel loads hoisted before use.
__global__ __launch_bounds__(256, 2) void norm_max_kernel(
    const unsigned short* __restrict__ y, const float* __restrict__ stats,
    const float* __restrict__ mult, float* __restrict__ out)
{
    const int blk = blockIdx.x;
    const int b   = blk >> 4;
    const int seg = blk & 15;
    const int tid = threadIdx.x;

    __shared__ float srs_s[OCH], snb_s[OCH], smul_s[OCH];
    if (tid < OCH) {
        const float s  = stats[(b * OCH + tid) * 2 + 0];
        const float sq = stats[(b * OCH + tid) * 2 + 1];
        const float mean = s * (1.0f / (float)SPATIAL);
        float var = sq * (1.0f / (float)SPATIAL) - mean * mean;
        var = fmaxf(var, 0.0f);
        const float rs = rsqrtf(var + EPSV);
        srs_s[tid]  = rs;
        snb_s[tid]  = -mean * rs;      // normalized = v*rs + nb
        smul_s[tid] = mult[tid];
    }
    __syncthreads();

    const int s = seg * 1024 + tid * 4;
    const unsigned short* yb = y + (size_t)b * OCH * SPATIAL + s;

    uint2 v[OCH];
#pragma unroll
    for (int c = 0; c < OCH; c++) {
        v[c] = *(const uint2*)(yb + (size_t)c * SPATIAL);
    }

    float rs[OCH], nb[OCH], mm[OCH];
#pragma unroll
    for (int c = 0; c < OCH; c++) { rs[c] = srs_s[c]; nb[c] = snb_s[c]; mm[c] = smul_s[c]; }

    float b0 = -INFINITY, b1 = -INFINITY, b2 = -INFINITY, b3 = -INFINITY;
#pragma unroll
    for (int c = 0; c < OCH; c++) {
        float f0 = __uint_as_float(v[c].x << 16)         * rs[c] + nb[c];
        float f1 = __uint_as_float(v[c].x & 0xffff0000u) * rs[c] + nb[c];
        float f2 = __uint_as_float(v[c].y << 16)         * rs[c] + nb[c];
        float f3 = __uint_as_float(v[c].y & 0xffff0000u) * rs[c] + nb[c];
        f0 = fminf(fmaxf(f0, -1.0f), 1.0f) * mm[c];
        f1 = fminf(fmaxf(f1, -1.0f), 1.0f) * mm[c];
        f2 = fminf(fmaxf(f2, -1.0f), 1.0f) * mm[c];
        f3 = fminf(fmaxf(f3, -1.0f), 1.0f) * mm[c];
        b0 = fmaxf(b0, f0); b1 = fmaxf(b1, f1);
        b2 = fmaxf(b2, f2); b3 = fmaxf(b3, f3);
    }
    float4 o; o.x = b0; o.y = b1; o.z = b2; o.w = b3;
    *(float4*)&out[(size_t)b * SPATIAL + s] = o;
}

extern "C" void kernel_launch(void* const* d_in, const int* in_sizes, int n_in,
                              void* d_out, int out_size, void* d_ws, size_t ws_size,
                              hipStream_t stream) {
    const float* x    = (const float*)d_in[0];
    const float* cw   = (const float*)d_in[1];
    const float* cb   = (const float*)d_in[2];
    const float* mult = (const float*)d_in[3];
    float* out = (float*)d_out;

    unsigned short* y = (unsigned short*)d_ws;   // channel-major, 64 MB
    float* stats = (float*)((char*)d_ws + (size_t)NB * OCH * SPATIAL * sizeof(unsigned short));

    hipMemsetAsync(stats, 0, (size_t)NB * OCH * 2 * sizeof(float), stream);
    conv_stats_kernel<<<NB * 8, 256, 0, stream>>>(x, cw, cb, mult, y, stats);
    norm_max_kernel<<<NB * 16, 256, 0, stream>>>(y, stats, mult, out);
}